// Round 5
// baseline (717.437 us; speedup 1.0000x reference)
//
#include <hip/hip_runtime.h>
#include <math.h>

typedef _Float16 f16_t;
typedef _Float16 f16x4 __attribute__((ext_vector_type(4)));
typedef _Float16 f16x8 __attribute__((ext_vector_type(8)));
typedef float f32x4 __attribute__((ext_vector_type(4)));

// Problem dims (fixed by setup_inputs)
constexpr int Bn = 128;       // batch
constexpr int Tn = 512;       // time steps
constexpr int Jn = 700;       // input features
constexpr int Jp = 704;       // padded to 32 multiple
constexpr int Hn = 512;       // hidden
constexpr int On = 20;        // output classes
constexpr int Mn = Bn * Tn;   // 65536 rows

#define LDS_U32(p) ((__attribute__((address_space(3))) uint32_t*)(p))
#define GLB_U32(p) ((const __attribute__((address_space(1))) uint32_t*)(p))

// ---------------------------------------------------------------------------
// SNN GEMM: C[M x Nout] = (A * W^T) * outScale, fp32-accuracy via folded
// hi/lo fp16 planes in K. 512 threads = 8 waves (2m x 4n) on a 128 x (NT*128)
// tile; each wave owns 64 x (NT*32) -> acc 4 x 2NT f32x4 = 32/64 VGPR, so
// __launch_bounds__(512,4) keeps total regs <=128 => 16 waves/CU (the round-4
// version sat at 224 regs -> 8 waves/CU -> 25% MfmaUtil).
// Per k-pair p (64 folded K): stage BOTH planes, ONE barrier pair, 64 MFMA
// per wave between barriers (halves barrier-drain count vs round 4).
// SPLIT=true (layer 1): A is raw fp32 x; hi/lo split done in-register during
// staging (ds_write_b128), removing the separate split_x kernel + its 368 MB.
// SPLIT=false: A is exact-f16 spikes, staged once per pair via lds-DMA.
// W always staged via global_load_lds (hi|lo folded rows, LDW = 2*KP).
// Epilogue: scale, store C, fused per-channel BN stats atomics.
// ---------------------------------------------------------------------------
template <int NT, bool SPLIT>
__global__ __launch_bounds__(512, 4) void gemm_snn(
    const void* __restrict__ Av, const f16_t* __restrict__ W,
    float* __restrict__ C, float* __restrict__ s_out, float* __restrict__ q_out,
    int LDA, int LDW, int KP, int pairs, int Nout, float outScale)
{
    constexpr int JT = 2 * NT;   // 16-col tiles per wave
    __shared__ __align__(16) f16_t sA[(SPLIT ? 2 : 1) * 128 * 32];
    __shared__ __align__(16) f16_t sW[NT * 2 * 128 * 32];

    const int tid  = threadIdx.x;
    const int bm   = blockIdx.y * 128;
    const int bn   = blockIdx.x * (NT * 128);
    const int lane = tid & 63;
    const int wv   = tid >> 6;              // 0..7
    const int wm   = (wv & 1) * 64;
    const int wn   = (wv >> 1) * (NT * 32);
    const int fr   = lane & 15;
    const int quad = lane >> 4;
    const int srow = lane >> 2;             // DMA: row within 16-row chunk
    const int scol = (lane & 3) * 8;        // DMA: f16 col offset

    f32x4 acc[4][JT];
#pragma unroll
    for (int i = 0; i < 4; ++i)
#pragma unroll
        for (int j = 0; j < JT; ++j) acc[i][j] = {0.f, 0.f, 0.f, 0.f};

    for (int p = 0; p < pairs; ++p) {
        // ---- stage W: NT*2 planes x 8 chunks of 16 rows, spread over waves ----
        for (int c = wv; c < NT * 16; c += 8) {
            const int h   = c / (NT * 8);
            const int rem = c % (NT * 8);
            const int nt  = rem >> 3;
            const int cr  = (rem & 7) * 16;
            const uint32_t off = __builtin_amdgcn_readfirstlane((h * NT + nt) * 8192 + cr * 64);
            const f16_t* gp = W + (size_t)(bn + nt * 128 + cr + srow) * LDW + h * KP + p * 32 + scol;
            __builtin_amdgcn_global_load_lds(GLB_U32(gp), LDS_U32((char*)sW + off), 16, 0, 0);
        }
        // ---- stage A ----
        if (SPLIT) {
            // fp32 x -> hi(32x)/lo planes, in-register, ds_write_b128.
            const int xrow = tid >> 2;             // 0..127
            const int xc   = (tid & 3) * 8;        // 0,8,16,24
            const int gk   = p * 32 + xc;
            const float* rp = (const float*)Av + (size_t)(bm + xrow) * LDA + gk;
            float f[8];
            if (gk + 8 <= LDA) {                   // LDA == Jn (valid cols)
                const float4 v0 = *(const float4*)rp;
                const float4 v1 = *(const float4*)(rp + 4);
                f[0] = v0.x; f[1] = v0.y; f[2] = v0.z; f[3] = v0.w;
                f[4] = v1.x; f[5] = v1.y; f[6] = v1.z; f[7] = v1.w;
            } else {
#pragma unroll
                for (int e = 0; e < 8; ++e) f[e] = (gk + e < LDA) ? rp[e] : 0.f;
            }
            f16x8 hv, lv;
#pragma unroll
            for (int e = 0; e < 8; ++e) {
                const float s = f[e] * 32.f;
                const f16_t h = (f16_t)s;
                hv[e] = h;
                lv[e] = (f16_t)(s - (float)h);
            }
            *(f16x8*)&sA[xrow * 32 + xc] = hv;
            *(f16x8*)&sA[4096 + xrow * 32 + xc] = lv;
        } else {
            // exact-f16 spikes: one 16-row chunk per wave via lds-DMA.
            const uint32_t off = __builtin_amdgcn_readfirstlane(wv * 1024);
            const f16_t* gp = (const f16_t*)Av + (size_t)(bm + wv * 16 + srow) * LDA + p * 32 + scol;
            __builtin_amdgcn_global_load_lds(GLB_U32(gp), LDS_U32((char*)sA + off), 16, 0, 0);
        }
        __syncthreads();

        // ---- consume both planes: 64 MFMA per wave between barriers ----
        if (SPLIT) {
#pragma unroll
            for (int h = 0; h < 2; ++h) {
                f16x8 av[4], wf[JT];
#pragma unroll
                for (int i = 0; i < 4; ++i)
                    av[i] = *(const f16x8*)&sA[h * 4096 + (wm + i * 16 + fr) * 32 + quad * 8];
#pragma unroll
                for (int jt = 0; jt < JT; ++jt) {
                    const int n  = wn + jt * 16 + fr;
                    wf[jt] = *(const f16x8*)&sW[(h * NT + (n >> 7)) * 4096 + (n & 127) * 32 + quad * 8];
                }
#pragma unroll
                for (int i = 0; i < 4; ++i)
#pragma unroll
                    for (int jt = 0; jt < JT; ++jt)
                        acc[i][jt] = __builtin_amdgcn_mfma_f32_16x16x32_f16(av[i], wf[jt], acc[i][jt], 0, 0, 0);
            }
        } else {
            f16x8 av[4];
#pragma unroll
            for (int i = 0; i < 4; ++i)
                av[i] = *(const f16x8*)&sA[(wm + i * 16 + fr) * 32 + quad * 8];
#pragma unroll
            for (int h = 0; h < 2; ++h) {
                f16x8 wf[JT];
#pragma unroll
                for (int jt = 0; jt < JT; ++jt) {
                    const int n  = wn + jt * 16 + fr;
                    wf[jt] = *(const f16x8*)&sW[(h * NT + (n >> 7)) * 4096 + (n & 127) * 32 + quad * 8];
                }
#pragma unroll
                for (int i = 0; i < 4; ++i)
#pragma unroll
                    for (int jt = 0; jt < JT; ++jt)
                        acc[i][jt] = __builtin_amdgcn_mfma_f32_16x16x32_f16(av[i], wf[jt], acc[i][jt], 0, 0, 0);
            }
        }
        __syncthreads();
    }

    // ---- epilogue: scale, store C, fused per-channel BN stats ----
#pragma unroll
    for (int jt = 0; jt < JT; ++jt) {
        const int gcol = bn + wn + jt * 16 + fr;
        float s = 0.f, q = 0.f;
        if (gcol < Nout) {
#pragma unroll
            for (int i = 0; i < 4; ++i) {
#pragma unroll
                for (int rg = 0; rg < 4; ++rg) {
                    const float v = acc[i][jt][rg] * outScale;
                    C[(size_t)(bm + wm + i * 16 + quad * 4 + rg) * Nout + gcol] = v;
                    s += v;
                    q += v * v;
                }
            }
        }
        s += __shfl_xor(s, 16); s += __shfl_xor(s, 32);
        q += __shfl_xor(q, 16); q += __shfl_xor(q, 32);
        if (quad == 0 && gcol < Nout) {
            atomicAdd(&s_out[gcol], s);
            atomicAdd(&q_out[gcol], q);
        }
    }
}

// ---------------------------------------------------------------------------
// W[N x K] fp32 -> Wo[NP x 2*KP] fp16 [hi(scale*W) | lo], zero pad rows/cols.
// ---------------------------------------------------------------------------
__global__ __launch_bounds__(256) void split_w(const float* __restrict__ Wsrc,
                                               f16_t* __restrict__ Wo,
                                               int N, int K, int KP, int NP, float scale) {
    const int idx = blockIdx.x * 256 + threadIdx.x;
    if (idx >= NP * KP) return;
    const int n = idx / KP, k = idx % KP;
    const float f = (n < N && k < K) ? Wsrc[(size_t)n * K + k] * scale : 0.f;
    const f16_t hi = (f16_t)f;
    const f16_t lo = (f16_t)(f - (float)hi);
    Wo[(size_t)n * (2 * KP) + k] = hi;
    Wo[(size_t)n * (2 * KP) + KP + k] = lo;
}

// ---------------------------------------------------------------------------
// LIF scan, 4 channels/thread: BN-normalize + sequential update + spike.
// float4 reads of pre-acts, f16x4 spike writes (exact 0/1 in f16).
// ---------------------------------------------------------------------------
__global__ __launch_bounds__(256) void lif_scan4(const float* __restrict__ X,
                                                 f16_t* __restrict__ S_out,
                                                 const float* __restrict__ sums,
                                                 const float* __restrict__ sumsq,
                                                 const float* __restrict__ beta_raw,
                                                 const float* __restrict__ gamma,
                                                 const float* __restrict__ bias) {
    const int gid = blockIdx.x * 256 + threadIdx.x;   // Bn * Hn/4 = 16384
    const int b  = gid >> 7;
    const int cq = gid & 127;          // float4 index within row
    const int c4 = cq * 4;

    float g[4], bi[4], bt[4], ob[4];
#pragma unroll
    for (int e = 0; e < 4; ++e) {
        const int i = c4 + e;
        const float invM = 1.f / (float)Mn;
        const float mean = sums[i] * invM;
        const float var  = sumsq[i] * invM - mean * mean;
        const float inv  = rsqrtf(var + 1e-5f);
        g[e]  = gamma[i] * inv;
        bi[e] = bias[i] - mean * g[e];
        bt[e] = 1.f / (1.f + expf(-beta_raw[i]));
        ob[e] = 1.f - bt[e];
    }

    const float4* Xp = (const float4*)X + (size_t)b * Tn * 128 + cq;
    f16x4* Sp4 = (f16x4*)S_out + (size_t)b * Tn * 128 + cq;

    float U[4] = {0.f, 0.f, 0.f, 0.f}, Sp[4] = {0.f, 0.f, 0.f, 0.f};
#pragma unroll 8
    for (int t = 0; t < Tn; ++t) {
        const float4 v = Xp[(size_t)t * 128];
        const float vf[4] = {v.x, v.y, v.z, v.w};
        f16x4 so;
#pragma unroll
        for (int e = 0; e < 4; ++e) {
            const float xt = vf[e] * g[e] + bi[e];
            U[e] = bt[e] * (U[e] - Sp[e]) + ob[e] * xt;
            Sp[e] = (U[e] > 1.0f) ? 1.0f : 0.0f;
            so[e] = (f16_t)Sp[e];
        }
        Sp4[(size_t)t * 128] = so;
    }
}

// ---------------------------------------------------------------------------
// Readout: BN + linear EMA scan + softmax over 20 classes + sum over T.
// ---------------------------------------------------------------------------
__global__ __launch_bounds__(256) void readout_kernel(const float* __restrict__ A,
                                                      const float* __restrict__ sums,
                                                      const float* __restrict__ sumsq,
                                                      const float* __restrict__ beta_raw,
                                                      const float* __restrict__ gamma,
                                                      const float* __restrict__ bias,
                                                      float* __restrict__ out) {
    __shared__ float xs[Tn * On];
    __shared__ float gsh[On], bsh[On], betash[On];
    __shared__ float red[4][On];

    const int b = blockIdx.x;
    const int tid = threadIdx.x;

    if (tid < On) {
        const float invM = 1.f / (float)Mn;
        const float mean = sums[tid] * invM;
        const float var = sumsq[tid] * invM - mean * mean;
        const float inv = rsqrtf(var + 1e-5f);
        const float g = gamma[tid] * inv;
        gsh[tid] = g;
        bsh[tid] = bias[tid] - mean * g;
        betash[tid] = 1.f / (1.f + expf(-beta_raw[tid]));
    }
    __syncthreads();

    const float* Ab = A + (size_t)b * Tn * On;
    for (int idx = tid; idx < Tn * On; idx += 256) {
        const int o = idx % On;
        xs[idx] = Ab[idx] * gsh[o] + bsh[o];
    }
    __syncthreads();

    if (tid < On) {
        const float beta = betash[tid], omb = 1.f - beta;
        float U = 0.f;
        for (int t = 0; t < Tn; ++t) {
            U = beta * U + omb * xs[t * On + tid];
            xs[t * On + tid] = U;
        }
    }
    __syncthreads();

    float part[On];
#pragma unroll
    for (int o = 0; o < On; ++o) part[o] = 0.f;

    for (int t = tid; t < Tn; t += 256) {
        float v[On];
        float m = -1e30f;
#pragma unroll
        for (int o = 0; o < On; ++o) {
            v[o] = xs[t * On + o];
            m = fmaxf(m, v[o]);
        }
        float s = 0.f;
#pragma unroll
        for (int o = 0; o < On; ++o) {
            v[o] = expf(v[o] - m);
            s += v[o];
        }
        const float rs = 1.f / s;
#pragma unroll
        for (int o = 0; o < On; ++o) part[o] += v[o] * rs;
    }

#pragma unroll
    for (int o = 0; o < On; ++o) {
#pragma unroll
        for (int off = 32; off > 0; off >>= 1) part[o] += __shfl_down(part[o], off);
    }
    const int lane = tid & 63, wid = tid >> 6;
    if (lane == 0) {
#pragma unroll
        for (int o = 0; o < On; ++o) red[wid][o] = part[o];
    }
    __syncthreads();
    if (tid < On) out[b * On + tid] = red[0][tid] + red[1][tid] + red[2][tid] + red[3][tid];
}

// ---------------------------------------------------------------------------
extern "C" void kernel_launch(void* const* d_in, const int* in_sizes, int n_in,
                              void* d_out, int out_size, void* d_ws, size_t ws_size,
                              hipStream_t stream) {
    const float* x   = (const float*)d_in[0];
    const float* W1  = (const float*)d_in[1];
    const float* be1 = (const float*)d_in[2];
    const float* g1  = (const float*)d_in[3];
    const float* b1  = (const float*)d_in[4];
    const float* W2  = (const float*)d_in[5];
    const float* be2 = (const float*)d_in[6];
    const float* b2g = (const float*)d_in[7];
    const float* b2  = (const float*)d_in[8];
    const float* Wr  = (const float*)d_in[9];
    const float* ber = (const float*)d_in[10];
    const float* gr  = (const float*)d_in[11];
    const float* br  = (const float*)d_in[12];
    float* out = (float*)d_out;

    char* ws = (char*)d_ws;
    const size_t bufCBytes = (size_t)Mn * Hn * sizeof(float);    // 134 MB
    const size_t bufSBytes = (size_t)Mn * Hn * sizeof(f16_t);    // 67 MB
    float*  bufC = (float*)ws;
    f16_t*  bufS = (f16_t*)(ws + bufCBytes);
    char*   p    = ws + bufCBytes + bufSBytes;
    float*  bufR = (float*)p;             p += (size_t)Mn * On * sizeof(float);
    f16_t*  W1s  = (f16_t*)p;             p += (size_t)Hn * (2 * Jp) * sizeof(f16_t);
    f16_t*  W2s  = (f16_t*)p;             p += (size_t)Hn * (2 * Hn) * sizeof(f16_t);
    f16_t*  Wrs  = (f16_t*)p;             p += (size_t)128 * (2 * Hn) * sizeof(f16_t);
    float*  stats = (float*)p;
    float* s1 = stats;       float* q1 = s1 + Hn;
    float* s2 = q1 + Hn;     float* q2 = s2 + Hn;
    float* s3 = q2 + Hn;     float* q3 = s3 + 32;

    hipMemsetAsync(stats, 0, (4 * Hn + 64) * sizeof(float), stream);

    // Weight hi|lo folded fp16 planes (scale 64).
    split_w<<<(Hn * Jp + 255) / 256, 256, 0, stream>>>(W1, W1s, Hn, Jn, Jp, Hn, 64.f);
    split_w<<<(Hn * Hn + 255) / 256, 256, 0, stream>>>(W2, W2s, Hn, Hn, Hn, Hn, 64.f);
    split_w<<<(128 * Hn + 255) / 256, 256, 0, stream>>>(Wr, Wrs, On, Hn, Hn, 128, 64.f);

    // Layer 1: x fp32 (in-kernel split, scale 32) * W1s -> bufC (scale 2^-11)
    gemm_snn<2, true><<<dim3(2, Mn / 128), 512, 0, stream>>>(x, W1s, bufC, s1, q1,
        Jn, 2 * Jp, Jp, Jp / 32, Hn, 1.f / 2048.f);
    lif_scan4<<<(Bn * Hn / 4) / 256, 256, 0, stream>>>(bufC, bufS, s1, q1, be1, g1, b1);

    // Layer 2: spikes f16 * W2s -> bufC (scale 2^-6)
    gemm_snn<2, false><<<dim3(2, Mn / 128), 512, 0, stream>>>(bufS, W2s, bufC, s2, q2,
        Hn, 2 * Hn, Hn, Hn / 32, Hn, 1.f / 64.f);
    lif_scan4<<<(Bn * Hn / 4) / 256, 256, 0, stream>>>(bufC, bufS, s2, q2, be2, b2g, b2);

    // Readout: spikes f16 * Wrs -> bufR [M x 20] (scale 2^-6)
    gemm_snn<1, false><<<dim3(1, Mn / 128), 512, 0, stream>>>(bufS, Wrs, bufR, s3, q3,
        Hn, 2 * Hn, Hn, Hn / 32, On, 1.f / 64.f);
    readout_kernel<<<Bn, 256, 0, stream>>>(bufR, s3, q3, ber, gr, br, out);
}

// Round 6
// 588.733 us; speedup vs baseline: 1.2186x; 1.2186x over previous
//
#include <hip/hip_runtime.h>
#include <math.h>

typedef _Float16 f16_t;
typedef _Float16 f16x8 __attribute__((ext_vector_type(8)));
typedef float f32x4 __attribute__((ext_vector_type(4)));

// Problem dims (fixed by setup_inputs)
constexpr int Bn = 128;       // batch
constexpr int Tn = 512;       // time steps
constexpr int Jn = 700;       // input features
constexpr int Jp = 704;       // padded to 64 multiple (11 x 64)
constexpr int Hn = 512;       // hidden
constexpr int On = 20;        // output classes
constexpr int Mn = Bn * Tn;   // 65536 rows

#define LDS_U32(p) ((__attribute__((address_space(3))) uint32_t*)(p))
#define GLB_U32(p) ((const __attribute__((address_space(1))) uint32_t*)(p))

// ---------------------------------------------------------------------------
// SNN MFMA GEMM, all-DMA staging + XOR bank swizzle.
//   C[M x Nout] = (A[M x LDA] * W^T) * outScale, fused BN-stats epilogue.
// MODE 0 (layer 1): plain f16 GEMM, BK=64 per barrier (two 32-k slices).
//   (f16 precision for layer 1 validated: round-5 diagonal-term kernel ==
//    hi-only to 2^-24 and passed with identical absmax.)
// MODE 1 (layers 2/3): A = exact-f16 spikes, one 32-k slice reused against
//   W's folded hi|lo planes (kW = h*KP + p*32) -> exact fp32-quality W.
// 512 thr = 8 waves (2m x 4n) on 128 x (NT*128); wave = 64x64 -> acc 64 AGPR.
// __launch_bounds__(512,4): <=128 regs/thread -> 2 blocks/CU = 16 waves/CU.
// Swizzle: DMA lane fetches global 16B-chunk (lane&3)^((lane>>3)&3); frag
// reads chunk quad^((fr>>1)&3) -> ds_read_b128 lands 2-way on banks (free)
// instead of 4-way (1.58x LDS penalty). LDS rows 64B, DMA-compatible.
// ---------------------------------------------------------------------------
template <int NT, int MODE>
__global__ __launch_bounds__(512, 4) void gemm_snn(
    const f16_t* __restrict__ A, const f16_t* __restrict__ W,
    float* __restrict__ C, float* __restrict__ s_out, float* __restrict__ q_out,
    int LDA, int LDW, int KP, int pairs, int Nout, float outScale)
{
    constexpr int JT = 2 * NT;              // 16-col tiles per wave
    constexpr int ASL = (MODE == 0) ? 2 : 1;  // A slices staged per barrier
    __shared__ __align__(16) f16_t sA[ASL * 4096];
    __shared__ __align__(16) f16_t sW[2 * NT * 4096];

    const int tid  = threadIdx.x;
    const int bm   = blockIdx.y * 128;
    const int bn   = blockIdx.x * (NT * 128);
    const int lane = tid & 63;
    const int wv   = tid >> 6;              // 0..7
    const int wm   = (wv & 1) * 64;
    const int wn   = (wv >> 1) * (NT * 32);
    const int fr   = lane & 15;
    const int quad = lane >> 4;
    const int srow = lane >> 2;                              // DMA row in chunk
    const int scol = (((lane & 3) ^ ((lane >> 3) & 3)) * 8); // swizzled fetch col
    const int ksw  = ((quad ^ ((fr >> 1) & 3)) * 8);         // swizzled frag col

    f32x4 acc[4][JT];
#pragma unroll
    for (int i = 0; i < 4; ++i)
#pragma unroll
        for (int j = 0; j < JT; ++j) acc[i][j] = {0.f, 0.f, 0.f, 0.f};

    for (int p = 0; p < pairs; ++p) {
        // ---- stage A: ASL slices x 8 chunks of 16 rows, spread over waves ----
#pragma unroll
        for (int cc = 0; cc < ASL; ++cc) {
            const int c  = wv + cc * 8;
            const int s  = c >> 3;
            const int cr = (c & 7) * 16;
            const int kA = (MODE == 0) ? p * 64 + s * 32 : p * 32;
            const uint32_t off = __builtin_amdgcn_readfirstlane(s * 8192 + cr * 64);
            const f16_t* gp = A + (size_t)(bm + cr + srow) * LDA + kA + scol;
            __builtin_amdgcn_global_load_lds(GLB_U32(gp), LDS_U32((char*)sA + off), 16, 0, 0);
        }
        // ---- stage W: 2 slices x NT tiles x 8 chunks ----
#pragma unroll
        for (int cc = 0; cc < 2 * NT; ++cc) {
            const int c   = wv + cc * 8;
            const int h   = c / (NT * 8);
            const int rem = c % (NT * 8);
            const int nt  = rem >> 3;
            const int cr  = (rem & 7) * 16;
            const int kW  = (MODE == 0) ? p * 64 + h * 32 : h * KP + p * 32;
            const uint32_t off = __builtin_amdgcn_readfirstlane((h * NT + nt) * 8192 + cr * 64);
            const f16_t* gp = W + (size_t)(bn + nt * 128 + cr + srow) * LDW + kW + scol;
            __builtin_amdgcn_global_load_lds(GLB_U32(gp), LDS_U32((char*)sW + off), 16, 0, 0);
        }
        __syncthreads();

        // ---- consume: 2 x 16 MFMA per wave between barriers ----
        f16x8 av[4];
#pragma unroll
        for (int h = 0; h < 2; ++h) {
            if (h == 0 || MODE == 0) {
                const int s = (MODE == 0) ? h : 0;
#pragma unroll
                for (int i = 0; i < 4; ++i)
                    av[i] = *(const f16x8*)&sA[s * 4096 + (wm + i * 16 + fr) * 32 + ksw];
            }
            f16x8 wf[JT];
#pragma unroll
            for (int jt = 0; jt < JT; ++jt) {
                const int n = wn + jt * 16 + fr;
                wf[jt] = *(const f16x8*)&sW[(h * NT + (n >> 7)) * 4096 + (n & 127) * 32 + ksw];
            }
#pragma unroll
            for (int i = 0; i < 4; ++i)
#pragma unroll
                for (int jt = 0; jt < JT; ++jt)
                    acc[i][jt] = __builtin_amdgcn_mfma_f32_16x16x32_f16(av[i], wf[jt], acc[i][jt], 0, 0, 0);
        }
        __syncthreads();
    }

    // ---- epilogue: scale, store C, fused per-channel BN stats ----
#pragma unroll
    for (int jt = 0; jt < JT; ++jt) {
        const int gcol = bn + wn + jt * 16 + fr;
        float s = 0.f, q = 0.f;
        if (gcol < Nout) {
#pragma unroll
            for (int i = 0; i < 4; ++i) {
#pragma unroll
                for (int rg = 0; rg < 4; ++rg) {
                    const float v = acc[i][jt][rg] * outScale;
                    C[(size_t)(bm + wm + i * 16 + quad * 4 + rg) * Nout + gcol] = v;
                    s += v;
                    q += v * v;
                }
            }
        }
        s += __shfl_xor(s, 16); s += __shfl_xor(s, 32);
        q += __shfl_xor(q, 16); q += __shfl_xor(q, 32);
        if (quad == 0 && gcol < Nout) {
            atomicAdd(&s_out[gcol], s);
            atomicAdd(&q_out[gcol], q);
        }
    }
}

// ---------------------------------------------------------------------------
// x[M x 700] fp32 -> A1[M x 704] f16 hi plane only (32x scale), zero-padded.
// ---------------------------------------------------------------------------
__global__ __launch_bounds__(256) void conv_a1(const float* __restrict__ x,
                                               f16_t* __restrict__ A1) {
    const int idx = blockIdx.x * 256 + threadIdx.x;   // Mn * 88 groups of 8
    const int m = idx / 88, g = idx % 88;
    const int k8 = g * 8;
    const float* rp = x + (size_t)m * Jn + k8;
    float f[8];
    if (k8 + 8 <= Jn) {
        const float4 v0 = *(const float4*)rp;
        const float4 v1 = *(const float4*)(rp + 4);
        f[0] = v0.x; f[1] = v0.y; f[2] = v0.z; f[3] = v0.w;
        f[4] = v1.x; f[5] = v1.y; f[6] = v1.z; f[7] = v1.w;
    } else {
#pragma unroll
        for (int e = 0; e < 8; ++e) f[e] = (k8 + e < Jn) ? rp[e] : 0.f;
    }
    f16x8 hv;
#pragma unroll
    for (int e = 0; e < 8; ++e) hv[e] = (f16_t)(f[e] * 32.f);
    *(f16x8*)&A1[(size_t)m * Jp + k8] = hv;
}

// ---------------------------------------------------------------------------
// W1[512 x 700] fp32 -> W1h[512 x 704] f16 (64x scale), zero-padded.
// ---------------------------------------------------------------------------
__global__ __launch_bounds__(256) void conv_w1(const float* __restrict__ Wsrc,
                                               f16_t* __restrict__ Wo) {
    const int idx = blockIdx.x * 256 + threadIdx.x;   // Hn * 88
    if (idx >= Hn * 88) return;
    const int n = idx / 88, g = idx % 88;
    const int k8 = g * 8;
    const float* rp = Wsrc + (size_t)n * Jn + k8;
    f16x8 hv;
#pragma unroll
    for (int e = 0; e < 8; ++e) {
        const float f = (k8 + e < Jn) ? rp[e] : 0.f;
        hv[e] = (f16_t)(f * 64.f);
    }
    *(f16x8*)&Wo[(size_t)n * Jp + k8] = hv;
}

// ---------------------------------------------------------------------------
// W[N x K] fp32 -> Wo[NP x 2*KP] f16 [hi(64W) | lo] folded planes, padded.
// ---------------------------------------------------------------------------
__global__ __launch_bounds__(256) void split_w(const float* __restrict__ Wsrc,
                                               f16_t* __restrict__ Wo,
                                               int N, int K, int KP, int NP) {
    const int idx = blockIdx.x * 256 + threadIdx.x;
    if (idx >= NP * KP) return;
    const int n = idx / KP, k = idx % KP;
    const float f = (n < N && k < K) ? Wsrc[(size_t)n * K + k] * 64.f : 0.f;
    const f16_t hi = (f16_t)f;
    const f16_t lo = (f16_t)(f - (float)hi);
    Wo[(size_t)n * (2 * KP) + k] = hi;
    Wo[(size_t)n * (2 * KP) + KP + k] = lo;
}

// ---------------------------------------------------------------------------
// LIF scan, 1 channel/thread (1024 waves -> 4 waves/CU for latency hiding):
// BN-normalize + sequential membrane update + spike (exact f16 0/1 out).
// ---------------------------------------------------------------------------
__global__ __launch_bounds__(256) void lif_scan1(const float* __restrict__ X,
                                                 f16_t* __restrict__ S_out,
                                                 const float* __restrict__ sums,
                                                 const float* __restrict__ sumsq,
                                                 const float* __restrict__ beta_raw,
                                                 const float* __restrict__ gamma,
                                                 const float* __restrict__ bias) {
    const int gid = blockIdx.x * 256 + threadIdx.x;   // Bn * Hn = 65536
    const int b = gid >> 9;
    const int i = gid & 511;

    const float invM = 1.f / (float)Mn;
    const float mean = sums[i] * invM;
    const float var  = sumsq[i] * invM - mean * mean;
    const float inv  = rsqrtf(var + 1e-5f);
    const float g    = gamma[i] * inv;
    const float bi   = bias[i] - mean * g;
    const float bt   = 1.f / (1.f + expf(-beta_raw[i]));
    const float ob   = 1.f - bt;

    const float* xp = X + (size_t)b * Tn * Hn + i;
    f16_t* sp = S_out + (size_t)b * Tn * Hn + i;

    float U = 0.f, Sp = 0.f;
#pragma unroll 8
    for (int t = 0; t < Tn; ++t) {
        const float xt = xp[(size_t)t * Hn] * g + bi;
        U = bt * (U - Sp) + ob * xt;
        Sp = (U > 1.0f) ? 1.0f : 0.0f;
        sp[(size_t)t * Hn] = (f16_t)Sp;
    }
}

// ---------------------------------------------------------------------------
// Readout: BN + linear EMA scan + softmax over 20 classes + sum over T.
// ---------------------------------------------------------------------------
__global__ __launch_bounds__(256) void readout_kernel(const float* __restrict__ A,
                                                      const float* __restrict__ sums,
                                                      const float* __restrict__ sumsq,
                                                      const float* __restrict__ beta_raw,
                                                      const float* __restrict__ gamma,
                                                      const float* __restrict__ bias,
                                                      float* __restrict__ out) {
    __shared__ float xs[Tn * On];
    __shared__ float gsh[On], bsh[On], betash[On];
    __shared__ float red[4][On];

    const int b = blockIdx.x;
    const int tid = threadIdx.x;

    if (tid < On) {
        const float invM = 1.f / (float)Mn;
        const float mean = sums[tid] * invM;
        const float var = sumsq[tid] * invM - mean * mean;
        const float inv = rsqrtf(var + 1e-5f);
        const float g = gamma[tid] * inv;
        gsh[tid] = g;
        bsh[tid] = bias[tid] - mean * g;
        betash[tid] = 1.f / (1.f + expf(-beta_raw[tid]));
    }
    __syncthreads();

    const float* Ab = A + (size_t)b * Tn * On;
    for (int idx = tid; idx < Tn * On; idx += 256) {
        const int o = idx % On;
        xs[idx] = Ab[idx] * gsh[o] + bsh[o];
    }
    __syncthreads();

    if (tid < On) {
        const float beta = betash[tid], omb = 1.f - beta;
        float U = 0.f;
        for (int t = 0; t < Tn; ++t) {
            U = beta * U + omb * xs[t * On + tid];
            xs[t * On + tid] = U;
        }
    }
    __syncthreads();

    float part[On];
#pragma unroll
    for (int o = 0; o < On; ++o) part[o] = 0.f;

    for (int t = tid; t < Tn; t += 256) {
        float v[On];
        float m = -1e30f;
#pragma unroll
        for (int o = 0; o < On; ++o) {
            v[o] = xs[t * On + o];
            m = fmaxf(m, v[o]);
        }
        float s = 0.f;
#pragma unroll
        for (int o = 0; o < On; ++o) {
            v[o] = expf(v[o] - m);
            s += v[o];
        }
        const float rs = 1.f / s;
#pragma unroll
        for (int o = 0; o < On; ++o) part[o] += v[o] * rs;
    }

#pragma unroll
    for (int o = 0; o < On; ++o) {
#pragma unroll
        for (int off = 32; off > 0; off >>= 1) part[o] += __shfl_down(part[o], off);
    }
    const int lane = tid & 63, wid = tid >> 6;
    if (lane == 0) {
#pragma unroll
        for (int o = 0; o < On; ++o) red[wid][o] = part[o];
    }
    __syncthreads();
    if (tid < On) out[b * On + tid] = red[0][tid] + red[1][tid] + red[2][tid] + red[3][tid];
}

// ---------------------------------------------------------------------------
extern "C" void kernel_launch(void* const* d_in, const int* in_sizes, int n_in,
                              void* d_out, int out_size, void* d_ws, size_t ws_size,
                              hipStream_t stream) {
    const float* x   = (const float*)d_in[0];
    const float* W1  = (const float*)d_in[1];
    const float* be1 = (const float*)d_in[2];
    const float* g1  = (const float*)d_in[3];
    const float* b1  = (const float*)d_in[4];
    const float* W2  = (const float*)d_in[5];
    const float* be2 = (const float*)d_in[6];
    const float* b2g = (const float*)d_in[7];
    const float* b2  = (const float*)d_in[8];
    const float* Wr  = (const float*)d_in[9];
    const float* ber = (const float*)d_in[10];
    const float* gr  = (const float*)d_in[11];
    const float* br  = (const float*)d_in[12];
    float* out = (float*)d_out;

    char* ws = (char*)d_ws;
    // Region 0: A1 (92 MB, dead after gemm1) overlapped with bufS (67 MB).
    const size_t r0Bytes   = (size_t)Mn * Jp * sizeof(f16_t);    // 92.3 MB
    const size_t bufCBytes = (size_t)Mn * Hn * sizeof(float);    // 134 MB
    f16_t* A1   = (f16_t*)ws;
    f16_t* bufS = (f16_t*)ws;                  // overlaps A1 (sequenced)
    float* bufC = (float*)(ws + r0Bytes);
    char*  p    = ws + r0Bytes + bufCBytes;
    float* bufR = (float*)p;              p += (size_t)Mn * On * sizeof(float);
    f16_t* W1h  = (f16_t*)p;              p += (size_t)Hn * Jp * sizeof(f16_t);
    f16_t* W2s  = (f16_t*)p;              p += (size_t)Hn * (2 * Hn) * sizeof(f16_t);
    f16_t* Wrs  = (f16_t*)p;              p += (size_t)128 * (2 * Hn) * sizeof(f16_t);
    float* stats = (float*)p;
    float* s1 = stats;       float* q1 = s1 + Hn;
    float* s2 = q1 + Hn;     float* q2 = s2 + Hn;
    float* s3 = q2 + Hn;     float* q3 = s3 + 32;

    hipMemsetAsync(stats, 0, (4 * Hn + 64) * sizeof(float), stream);

    // Conversions (memory-bound, no split work inside GEMM K-loops).
    conv_a1<<<(Mn * 88) / 256, 256, 0, stream>>>(x, A1);
    conv_w1<<<(Hn * 88 + 255) / 256, 256, 0, stream>>>(W1, W1h);
    split_w<<<(Hn * Hn + 255) / 256, 256, 0, stream>>>(W2, W2s, Hn, Hn, Hn, Hn);
    split_w<<<(128 * Hn + 255) / 256, 256, 0, stream>>>(Wr, Wrs, On, Hn, Hn, 128);

    // Layer 1: plain f16 GEMM (validated precision), K=704, scale 2^-11.
    gemm_snn<2, 0><<<dim3(2, Mn / 128), 512, 0, stream>>>(A1, W1h, bufC, s1, q1,
        Jp, Jp, 0, Jp / 64, Hn, 1.f / 2048.f);
    lif_scan1<<<Mn * Hn / (512 * 256), 256, 0, stream>>>(bufC, bufS, s1, q1, be1, g1, b1);

    // Layer 2: exact spikes x folded (Whi|Wlo), scale 2^-6.
    gemm_snn<2, 1><<<dim3(2, Mn / 128), 512, 0, stream>>>(bufS, W2s, bufC, s2, q2,
        Hn, 2 * Hn, Hn, Hn / 32, Hn, 1.f / 64.f);
    lif_scan1<<<Mn * Hn / (512 * 256), 256, 0, stream>>>(bufC, bufS, s2, q2, be2, b2g, b2);

    // Readout: spikes x folded Wr -> [M x 20], scale 2^-6.
    gemm_snn<1, 1><<<dim3(1, Mn / 128), 512, 0, stream>>>(bufS, Wrs, bufR, s3, q3,
        Hn, 2 * Hn, Hn, Hn / 32, On, 1.f / 64.f);
    readout_kernel<<<Bn, 256, 0, stream>>>(bufR, s3, q3, ber, gr, br, out);
}

// Round 8
// 562.338 us; speedup vs baseline: 1.2758x; 1.0469x over previous
//
#include <hip/hip_runtime.h>
#include <math.h>

typedef _Float16 f16_t;
typedef _Float16 f16x2 __attribute__((ext_vector_type(2)));
typedef _Float16 f16x8 __attribute__((ext_vector_type(8)));
typedef float f32x4 __attribute__((ext_vector_type(4)));

// Problem dims (fixed by setup_inputs)
constexpr int Bn = 128;       // batch
constexpr int Tn = 512;       // time steps
constexpr int Jn = 700;       // input features
constexpr int Jp = 704;       // padded to 64 multiple (11 x 64)
constexpr int Hn = 512;       // hidden
constexpr int On = 20;        // output classes
constexpr int Mn = Bn * Tn;   // 65536 rows

#define LDS_U32(p) ((__attribute__((address_space(3))) uint32_t*)(p))
#define GLB_U32(p) ((const __attribute__((address_space(1))) uint32_t*)(p))

// ---------------------------------------------------------------------------
// Plain-f16 MFMA GEMM, fp32 C output (round-6 numerics for C; W-f16 for
// layers 2/3 is this round's single bisected numerics change).
//   C[M x Nout](fp32) = A[M x LDA](f16) * W[NP x LDW](f16)^T
// BK=64 per barrier (two 32-k slices), all staging via global_load_lds,
// XOR bank swizzle (fetch chunk (lane&3)^((lane>>3)&3), frag chunk
// quad^((fr>>1)&3)) -> ds_read_b128 lands 2-way on banks (free, m136).
// 512 thr = 8 waves (2m x 4n) on 128 x (NT*128); wave = 64 x (NT*32).
// __launch_bounds__(512,4): regs <=128 -> 2 blocks/CU = 16 waves/CU.
// SWZ: XCD-pairing 1-D grid map. Linear ids g and g+8 land on the same XCD
// (round-robin %8); map them to the two N-blocks of the same A-stripe
// (y=(g>>4)*8+(g&7), x=(g>>3)&1) so the A-stripe is fetched into one XCD's
// L2 once instead of two (round-5 counter: 194 MB fetch for 92 MB operand).
// Epilogue: fp32 store + fused per-channel BN stats atomics.
// ---------------------------------------------------------------------------
template <int NT, bool SWZ>
__global__ __launch_bounds__(512, 4) void gemm_f16(
    const f16_t* __restrict__ A, const f16_t* __restrict__ W,
    float* __restrict__ C, float* __restrict__ s_out, float* __restrict__ q_out,
    int LDA, int LDW, int pairs, int Nout)
{
    constexpr int JT = 2 * NT;              // 16-col tiles per wave
    __shared__ __align__(16) f16_t sA[2 * 4096];
    __shared__ __align__(16) f16_t sW[2 * NT * 4096];

    int bx, by;
    if (SWZ) {
        const int g = blockIdx.x;
        by = (g >> 4) * 8 + (g & 7);
        bx = (g >> 3) & 1;
    } else {
        bx = blockIdx.x;
        by = blockIdx.y;
    }
    const int tid  = threadIdx.x;
    const int bm   = by * 128;
    const int bn   = bx * (NT * 128);
    const int lane = tid & 63;
    const int wv   = tid >> 6;              // 0..7
    const int wm   = (wv & 1) * 64;
    const int wn   = (wv >> 1) * (NT * 32);
    const int fr   = lane & 15;
    const int quad = lane >> 4;
    const int srow = lane >> 2;                              // DMA row in chunk
    const int scol = (((lane & 3) ^ ((lane >> 3) & 3)) * 8); // swizzled fetch col
    const int ksw  = ((quad ^ ((fr >> 1) & 3)) * 8);         // swizzled frag col

    f32x4 acc[4][JT];
#pragma unroll
    for (int i = 0; i < 4; ++i)
#pragma unroll
        for (int j = 0; j < JT; ++j) acc[i][j] = {0.f, 0.f, 0.f, 0.f};

    for (int p = 0; p < pairs; ++p) {
        // ---- stage A: 2 k-slices x 8 chunks of 16 rows, spread over waves ----
#pragma unroll
        for (int cc = 0; cc < 2; ++cc) {
            const int c  = wv + cc * 8;     // 0..15
            const int s  = c >> 3;
            const int cr = (c & 7) * 16;
            const int kA = p * 64 + s * 32;
            const uint32_t off = __builtin_amdgcn_readfirstlane(s * 8192 + cr * 64);
            const f16_t* gp = A + (size_t)(bm + cr + srow) * LDA + kA + scol;
            __builtin_amdgcn_global_load_lds(GLB_U32(gp), LDS_U32((char*)sA + off), 16, 0, 0);
        }
        // ---- stage W: 2 k-slices x NT tiles x 8 chunks ----
#pragma unroll
        for (int cc = 0; cc < 2 * NT; ++cc) {
            const int c   = wv + cc * 8;
            const int h   = c / (NT * 8);
            const int rem = c % (NT * 8);
            const int nt  = rem >> 3;
            const int cr  = (rem & 7) * 16;
            const int kW  = p * 64 + h * 32;
            const uint32_t off = __builtin_amdgcn_readfirstlane((h * NT + nt) * 8192 + cr * 64);
            const f16_t* gp = W + (size_t)(bn + nt * 128 + cr + srow) * LDW + kW + scol;
            __builtin_amdgcn_global_load_lds(GLB_U32(gp), LDS_U32((char*)sW + off), 16, 0, 0);
        }
        __syncthreads();

        // ---- consume: 2 x (4 x JT) MFMA per wave between barriers ----
#pragma unroll
        for (int h = 0; h < 2; ++h) {
            f16x8 av[4];
#pragma unroll
            for (int i = 0; i < 4; ++i)
                av[i] = *(const f16x8*)&sA[h * 4096 + (wm + i * 16 + fr) * 32 + ksw];
            f16x8 wf[JT];
#pragma unroll
            for (int jt = 0; jt < JT; ++jt) {
                const int n = wn + jt * 16 + fr;
                wf[jt] = *(const f16x8*)&sW[(h * NT + (n >> 7)) * 4096 + (n & 127) * 32 + ksw];
            }
#pragma unroll
            for (int i = 0; i < 4; ++i)
#pragma unroll
                for (int jt = 0; jt < JT; ++jt)
                    acc[i][jt] = __builtin_amdgcn_mfma_f32_16x16x32_f16(av[i], wf[jt], acc[i][jt], 0, 0, 0);
        }
        __syncthreads();
    }

    // ---- epilogue: fp32 store + fused per-channel BN stats ----
#pragma unroll
    for (int jt = 0; jt < JT; ++jt) {
        const int gcol = bn + wn + jt * 16 + fr;
        float s = 0.f, q = 0.f;
        if (gcol < Nout) {
#pragma unroll
            for (int i = 0; i < 4; ++i) {
#pragma unroll
                for (int rg = 0; rg < 4; ++rg) {
                    const float v = acc[i][jt][rg];
                    C[(size_t)(bm + wm + i * 16 + quad * 4 + rg) * Nout + gcol] = v;
                    s += v;
                    q += v * v;
                }
            }
        }
        s += __shfl_xor(s, 16); s += __shfl_xor(s, 32);
        q += __shfl_xor(q, 16); q += __shfl_xor(q, 32);
        if (quad == 0 && gcol < Nout) {
            atomicAdd(&s_out[gcol], s);
            atomicAdd(&q_out[gcol], q);
        }
    }
}

// ---------------------------------------------------------------------------
// x[M x 700] fp32 -> A1[M x 704] f16, zero-padded.
// ---------------------------------------------------------------------------
__global__ __launch_bounds__(256) void conv_x(const float* __restrict__ x,
                                              f16_t* __restrict__ A1) {
    const int idx = blockIdx.x * 256 + threadIdx.x;   // Mn * 88 groups of 8
    const int m = idx / 88, g = idx % 88;
    const int k8 = g * 8;
    const float* rp = x + (size_t)m * Jn + k8;
    float f[8];
    if (k8 + 8 <= Jn) {
        const float4 v0 = *(const float4*)rp;
        const float4 v1 = *(const float4*)(rp + 4);
        f[0] = v0.x; f[1] = v0.y; f[2] = v0.z; f[3] = v0.w;
        f[4] = v1.x; f[5] = v1.y; f[6] = v1.z; f[7] = v1.w;
    } else {
#pragma unroll
        for (int e = 0; e < 8; ++e) f[e] = (k8 + e < Jn) ? rp[e] : 0.f;
    }
    f16x8 hv;
#pragma unroll
    for (int e = 0; e < 8; ++e) hv[e] = (f16_t)f[e];
    *(f16x8*)&A1[(size_t)m * Jp + k8] = hv;
}

// ---------------------------------------------------------------------------
// W[N x K] fp32 -> Wo[NP x KP] f16, zero-padded rows/cols. 8 elems/thread.
// ---------------------------------------------------------------------------
__global__ __launch_bounds__(256) void conv_w(const float* __restrict__ Wsrc,
                                              f16_t* __restrict__ Wo,
                                              int N, int K, int KP, int NP) {
    const int idx = blockIdx.x * 256 + threadIdx.x;
    if (idx >= NP * (KP / 8)) return;
    const int n = idx / (KP / 8), g = idx % (KP / 8);
    const int k8 = g * 8;
    f16x8 hv;
#pragma unroll
    for (int e = 0; e < 8; ++e) {
        const float f = (n < N && k8 + e < K) ? Wsrc[(size_t)n * K + k8 + e] : 0.f;
        hv[e] = (f16_t)f;
    }
    *(f16x8*)&Wo[(size_t)n * KP + k8] = hv;
}

// ---------------------------------------------------------------------------
// LIF scan, 2 channels/thread: BN-normalize (fp32 pre-acts) + sequential
// membrane update + spike. float2 reads, f16x2 writes (256 B/wave stores).
// ---------------------------------------------------------------------------
__global__ __launch_bounds__(256) void lif_scan(const float* __restrict__ X,
                                                f16_t* __restrict__ S_out,
                                                const float* __restrict__ sums,
                                                const float* __restrict__ sumsq,
                                                const float* __restrict__ beta_raw,
                                                const float* __restrict__ gamma,
                                                const float* __restrict__ bias) {
    const int gid = blockIdx.x * 256 + threadIdx.x;   // Bn * Hn/2 = 32768
    const int b  = gid >> 8;
    const int cq = gid & 255;          // float2 index within row
    const int i0 = cq * 2;

    float g[2], bi[2], bt[2], ob[2];
#pragma unroll
    for (int e = 0; e < 2; ++e) {
        const int i = i0 + e;
        const float invM = 1.f / (float)Mn;
        const float mean = sums[i] * invM;
        const float var  = sumsq[i] * invM - mean * mean;
        const float inv  = rsqrtf(var + 1e-5f);
        g[e]  = gamma[i] * inv;
        bi[e] = bias[i] - mean * g[e];
        bt[e] = 1.f / (1.f + expf(-beta_raw[i]));
        ob[e] = 1.f - bt[e];
    }

    const float2* Xp = (const float2*)(X + (size_t)b * Tn * Hn) + cq;
    f16x2* Sp2 = (f16x2*)(S_out + (size_t)b * Tn * Hn) + cq;

    float U[2] = {0.f, 0.f}, Sp[2] = {0.f, 0.f};
#pragma unroll 8
    for (int t = 0; t < Tn; ++t) {
        const float2 v = Xp[(size_t)t * (Hn / 2)];
        const float vf[2] = {v.x, v.y};
        f16x2 so;
#pragma unroll
        for (int e = 0; e < 2; ++e) {
            const float xt = vf[e] * g[e] + bi[e];
            U[e] = bt[e] * (U[e] - Sp[e]) + ob[e] * xt;
            Sp[e] = (U[e] > 1.0f) ? 1.0f : 0.0f;
            so[e] = (f16_t)Sp[e];
        }
        Sp2[(size_t)t * (Hn / 2)] = so;
    }
}

// ---------------------------------------------------------------------------
// Readout: BN + linear EMA scan + softmax over 20 classes + sum over T.
// ---------------------------------------------------------------------------
__global__ __launch_bounds__(256) void readout_kernel(const float* __restrict__ A,
                                                      const float* __restrict__ sums,
                                                      const float* __restrict__ sumsq,
                                                      const float* __restrict__ beta_raw,
                                                      const float* __restrict__ gamma,
                                                      const float* __restrict__ bias,
                                                      float* __restrict__ out) {
    __shared__ float xs[Tn * On];
    __shared__ float gsh[On], bsh[On], betash[On];
    __shared__ float red[4][On];

    const int b = blockIdx.x;
    const int tid = threadIdx.x;

    if (tid < On) {
        const float invM = 1.f / (float)Mn;
        const float mean = sums[tid] * invM;
        const float var = sumsq[tid] * invM - mean * mean;
        const float inv = rsqrtf(var + 1e-5f);
        const float g = gamma[tid] * inv;
        gsh[tid] = g;
        bsh[tid] = bias[tid] - mean * g;
        betash[tid] = 1.f / (1.f + expf(-beta_raw[tid]));
    }
    __syncthreads();

    const float* Ab = A + (size_t)b * Tn * On;
    for (int idx = tid; idx < Tn * On; idx += 256) {
        const int o = idx % On;
        xs[idx] = Ab[idx] * gsh[o] + bsh[o];
    }
    __syncthreads();

    if (tid < On) {
        const float beta = betash[tid], omb = 1.f - beta;
        float U = 0.f;
        for (int t = 0; t < Tn; ++t) {
            U = beta * U + omb * xs[t * On + tid];
            xs[t * On + tid] = U;
        }
    }
    __syncthreads();

    float part[On];
#pragma unroll
    for (int o = 0; o < On; ++o) part[o] = 0.f;

    for (int t = tid; t < Tn; t += 256) {
        float v[On];
        float m = -1e30f;
#pragma unroll
        for (int o = 0; o < On; ++o) {
            v[o] = xs[t * On + o];
            m = fmaxf(m, v[o]);
        }
        float s = 0.f;
#pragma unroll
        for (int o = 0; o < On; ++o) {
            v[o] = expf(v[o] - m);
            s += v[o];
        }
        const float rs = 1.f / s;
#pragma unroll
        for (int o = 0; o < On; ++o) part[o] += v[o] * rs;
    }

#pragma unroll
    for (int o = 0; o < On; ++o) {
#pragma unroll
        for (int off = 32; off > 0; off >>= 1) part[o] += __shfl_down(part[o], off);
    }
    const int lane = tid & 63, wid = tid >> 6;
    if (lane == 0) {
#pragma unroll
        for (int o = 0; o < On; ++o) red[wid][o] = part[o];
    }
    __syncthreads();
    if (tid < On) out[b * On + tid] = red[0][tid] + red[1][tid] + red[2][tid] + red[3][tid];
}

// ---------------------------------------------------------------------------
extern "C" void kernel_launch(void* const* d_in, const int* in_sizes, int n_in,
                              void* d_out, int out_size, void* d_ws, size_t ws_size,
                              hipStream_t stream) {
    const float* x   = (const float*)d_in[0];
    const float* W1  = (const float*)d_in[1];
    const float* be1 = (const float*)d_in[2];
    const float* g1  = (const float*)d_in[3];
    const float* b1  = (const float*)d_in[4];
    const float* W2  = (const float*)d_in[5];
    const float* be2 = (const float*)d_in[6];
    const float* b2g = (const float*)d_in[7];
    const float* b2  = (const float*)d_in[8];
    const float* Wr  = (const float*)d_in[9];
    const float* ber = (const float*)d_in[10];
    const float* gr  = (const float*)d_in[11];
    const float* br  = (const float*)d_in[12];
    float* out = (float*)d_out;

    char* ws = (char*)d_ws;
    // Region 0: A1 (92 MB, dead after gemm1) overlapped with bufS (67 MB).
    const size_t r0Bytes   = (size_t)Mn * Jp * sizeof(f16_t);    // 92.3 MB
    const size_t bufCBytes = (size_t)Mn * Hn * sizeof(float);    // 134 MB fp32
    f16_t* A1   = (f16_t*)ws;
    f16_t* bufS = (f16_t*)ws;                  // overlaps A1 (sequenced)
    float* bufC = (float*)(ws + r0Bytes);
    char*  p    = ws + r0Bytes + bufCBytes;
    float* bufR = (float*)p;              p += (size_t)Mn * On * sizeof(float);
    f16_t* W1h  = (f16_t*)p;              p += (size_t)Hn * Jp * sizeof(f16_t);
    f16_t* W2h  = (f16_t*)p;              p += (size_t)Hn * Hn * sizeof(f16_t);
    f16_t* Wrh  = (f16_t*)p;              p += (size_t)128 * Hn * sizeof(f16_t);
    float* stats = (float*)p;
    float* s1 = stats;       float* q1 = s1 + Hn;
    float* s2 = q1 + Hn;     float* q2 = s2 + Hn;
    float* s3 = q2 + Hn;     float* q3 = s3 + 32;

    hipMemsetAsync(stats, 0, (4 * Hn + 64) * sizeof(float), stream);

    // f16 conversions (memory-bound; no conversion work inside GEMM K-loops).
    conv_x<<<(Mn * 88) / 256, 256, 0, stream>>>(x, A1);
    conv_w<<<(Hn * 88 + 255) / 256, 256, 0, stream>>>(W1, W1h, Hn, Jn, Jp, Hn);
    conv_w<<<(Hn * 64 + 255) / 256, 256, 0, stream>>>(W2, W2h, Hn, Hn, Hn, Hn);
    conv_w<<<(128 * 64 + 255) / 256, 256, 0, stream>>>(Wr, Wrh, On, Hn, Hn, 128);

    // Layer 1: A1[M x 704] * W1h[512 x 704]^T -> bufC fp32, fused s1/q1.
    gemm_f16<2, true><<<2 * (Mn / 128), 512, 0, stream>>>(A1, W1h, bufC, s1, q1,
        Jp, Jp, Jp / 64, Hn);
    lif_scan<<<(Bn * Hn / 2) / 256, 256, 0, stream>>>(bufC, bufS, s1, q1, be1, g1, b1);

    // Layer 2: spikes[M x 512] * W2h[512 x 512]^T -> bufC fp32, fused s2/q2.
    gemm_f16<2, true><<<2 * (Mn / 128), 512, 0, stream>>>(bufS, W2h, bufC, s2, q2,
        Hn, Hn, Hn / 64, Hn);
    lif_scan<<<(Bn * Hn / 2) / 256, 256, 0, stream>>>(bufC, bufS, s2, q2, be2, b2g, b2);

    // Readout: spikes[M x 512] * Wrh[128 x 512]^T -> bufR[M x 20] fp32.
    gemm_f16<1, false><<<dim3(1, Mn / 128), 512, 0, stream>>>(bufS, Wrh, bufR, s3, q3,
        Hn, Hn, Hn / 64, On);
    readout_kernel<<<Bn, 256, 0, stream>>>(bufR, s3, q3, ber, gr, br, out);
}